// Round 5
// baseline (29.278 us; speedup 1.0000x reference)
//
#include <hip/hip_runtime.h>
#include <math.h>

// Problem constants (from reference setup_inputs): B=2, S=1024, F=512, N=128.
#define F 512
#define N 128
#define G 256                 // density-table points per feature
#define ROWS 4                // fallback kernel rows/block

constexpr float PROB_THRESHOLD = 0.3f;
constexpr float MARGIN         = 1e-4f;   // certified interp error bound x ~14
constexpr float INV_SQRT_2PI   = 0.3989422804014327f;
// exp(-0.5*z^2) = exp2(-(z*SCALE_C)^2), SCALE_C = sqrt(0.5*log2(e))
constexpr float SCALE_C = 0.8493218002880191f;
// 128^(-0.2)  (Scott's rule factor)
constexpr float FACTOR  = 0.37892914162759955f;
constexpr float PAD_T   = 8.0f;           // grid padding in t-units (exp2(-64)~0)

// ---------------------------------------------------------------------------
// Kernel 1: per-feature stats, one WAVE per feature (validated in R2).
// Adds min/max butterflies to define the density grid range.
//   scale = SCALE_C/bw, coef = INV_SQRT_2PI/bw,
//   t0 = min(a)-PAD_T, inv_ht = (G-1)/(t1-t0) with t1 = max(a)+PAD_T.
// ---------------------------------------------------------------------------
__global__ __launch_bounds__(512) void kde_stats(const float* __restrict__ kde,
                                                 float* __restrict__ scale_o,
                                                 float* __restrict__ coef_o,
                                                 float* __restrict__ t0_o,
                                                 float* __restrict__ invht_o) {
    const int lane = threadIdx.x & 63;
    const int f    = blockIdx.x * 8 + (threadIdx.x >> 6);  // one wave per feature

    const float v0 = kde[lane * F + f];
    const float v1 = kde[(lane + 64) * F + f];

    float s = v0 + v1;
#pragma unroll
    for (int off = 32; off >= 1; off >>= 1) s += __shfl_xor(s, off);
    const float mean = s * (1.0f / N);

    const float d0 = v0 - mean, d1 = v1 - mean;
    float ss = fmaf(d0, d0, d1 * d1);
#pragma unroll
    for (int off = 32; off >= 1; off >>= 1) ss += __shfl_xor(ss, off);

    float mn = fminf(v0, v1), mx = fmaxf(v0, v1);
#pragma unroll
    for (int off = 32; off >= 1; off >>= 1) {
        mn = fminf(mn, __shfl_xor(mn, off));
        mx = fmaxf(mx, __shfl_xor(mx, off));
    }

    const float var   = ss * (1.0f / (N - 1));
    const float bw    = FACTOR * sqrtf(var);
    const float scale = SCALE_C / bw;

    if (lane == 0) {
        const float t0 = mn * scale - PAD_T;
        const float t1 = mx * scale + PAD_T;
        scale_o[f] = scale;
        coef_o[f]  = INV_SQRT_2PI / bw;
        t0_o[f]    = t0;
        invht_o[f] = (float)(G - 1) / (t1 - t0);
    }
}

// ---------------------------------------------------------------------------
// Kernel 2: build per-feature density table (dens units). One block per
// feature, G threads (one per grid point), 128 exps per thread.
// ---------------------------------------------------------------------------
__global__ __launch_bounds__(G) void kde_build(const float* __restrict__ kde,
                                               const float* __restrict__ scale_p,
                                               const float* __restrict__ coef_p,
                                               const float* __restrict__ t0_p,
                                               const float* __restrict__ invht_p,
                                               float* __restrict__ table) {
    const int f = blockIdx.x;
    const int g = threadIdx.x;
    const float scale = scale_p[f];
    const float coef  = coef_p[f];
    const float t0    = t0_p[f];
    const float ht    = 1.0f / invht_p[f];

    __shared__ float la[N];
    if (g < N) la[g] = kde[g * F + f] * scale;
    __syncthreads();

    const float tg = fmaf((float)g, ht, t0);
    float acc = 0.f;
#pragma unroll 8
    for (int n = 0; n < N; ++n) {
        const float z = tg - la[n];
        acc += __builtin_amdgcn_exp2f(-(z * z));
    }
    table[f * G + g] = (acc * (1.0f / N)) * coef;
}

// ---------------------------------------------------------------------------
// Kernel 3: apply. One thread per element; cubic Lagrange interp of the
// density table; ambiguous band (|dens-0.3|<MARGIN) recomputed exactly with
// R3's validated arithmetic.
// ---------------------------------------------------------------------------
__global__ __launch_bounds__(256) void kde_apply(const float* __restrict__ x,
                                                 const float* __restrict__ kde,
                                                 const float* __restrict__ repl,
                                                 const float* __restrict__ scale_p,
                                                 const float* __restrict__ coef_p,
                                                 const float* __restrict__ t0_p,
                                                 const float* __restrict__ invht_p,
                                                 const float* __restrict__ table,
                                                 float* __restrict__ out) {
    const int e = blockIdx.x * 256 + threadIdx.x;
    const int f = e & (F - 1);

    const float xv    = x[e];
    const float scale = scale_p[f];
    const float t     = xv * scale;
    const float u     = (t - t0_p[f]) * invht_p[f];

    float res      = xv;
    bool ambiguous = false;

    if (u >= 1.0f && u < (float)(G - 2)) {
        const int   i = (int)u;          // floor (u >= 1)
        const float s = u - (float)i;
        const int   base = f * G + i - 1;
        const float p0 = table[base + 0];
        const float p1 = table[base + 1];
        const float p2 = table[base + 2];
        const float p3 = table[base + 3];
        const float sm1 = s - 1.0f, sm2 = s - 2.0f, sp1 = s + 1.0f;
        const float w0 = -s * sm1 * sm2 * (1.0f / 6.0f);
        const float w1 = sp1 * sm1 * sm2 * 0.5f;
        const float w2 = -sp1 * s * sm2 * 0.5f;
        const float w3 = sp1 * s * sm1 * (1.0f / 6.0f);
        const float dens = w0 * p0 + w1 * p1 + w2 * p2 + w3 * p3;

        if (dens >= PROB_THRESHOLD + MARGIN) {
            res = repl[f];
        } else if (dens >= PROB_THRESHOLD - MARGIN) {
            ambiguous = true;
        }
    }
    // (u out of range => nearest sample >= ~7.9 t-units => dens < 1e-18 => keep x)

    if (ambiguous) {
        // Exact recompute — bitwise R3 arithmetic (validated absmax=0).
        const float coef = coef_p[f];
        const float t2   = t + t;
        const float et   = __builtin_amdgcn_exp2f(-(t * t));
        float acc = 0.f;
        for (int n = 0; n < N; ++n) {
            const float a   = kde[n * F + f] * scale;
            const float na2 = -(a * a);
            acc += __builtin_amdgcn_exp2f(fmaf(t2, a, na2));
        }
        const float sum  = acc * et;
        const float dens = (sum * (1.0f / N)) * coef;
        res = (dens >= PROB_THRESHOLD) ? repl[f] : xv;
    }

    out[e] = res;
}

// ---------------------------------------------------------------------------
// Fallback (ws too small): R4's validated fused kernel, unchanged.
// ---------------------------------------------------------------------------
__global__ __launch_bounds__(512) void kde_mask_fused(const float* __restrict__ x,
                                                      const float* __restrict__ kde,
                                                      const float* __restrict__ repl,
                                                      float* __restrict__ out) {
    const int f  = threadIdx.x;
    const int r0 = blockIdx.x * ROWS;

    float s = 0.f, ss = 0.f;
#pragma unroll 8
    for (int n = 0; n < N; ++n) {
        const float v = kde[n * F + f];
        s += v;
        ss = fmaf(v, v, ss);
    }
    const float mean  = s * (1.0f / N);
    const float var   = (ss - s * mean) * (1.0f / (N - 1));
    const float bw    = FACTOR * sqrtf(var);
    const float scale = SCALE_C / bw;
    const float coef  = INV_SQRT_2PI / bw;

    float xv[ROWS], t2[ROWS], et[ROWS], acc[ROWS];
#pragma unroll
    for (int k = 0; k < ROWS; ++k) {
        xv[k]  = x[(r0 + k) * F + f];
        const float t = xv[k] * scale;
        t2[k]  = t + t;
        et[k]  = __builtin_amdgcn_exp2f(-(t * t));
        acc[k] = 0.f;
    }
#pragma unroll 8
    for (int n = 0; n < N; ++n) {
        const float v   = kde[n * F + f];
        const float a   = v * scale;
        const float na2 = -(a * a);
#pragma unroll
        for (int k = 0; k < ROWS; ++k) {
            acc[k] += __builtin_amdgcn_exp2f(fmaf(t2[k], a, na2));
        }
    }
    const float rv = repl[f];
#pragma unroll
    for (int k = 0; k < ROWS; ++k) {
        const float sum  = acc[k] * et[k];
        const float dens = (sum * (1.0f / N)) * coef;
        out[(r0 + k) * F + f] = (dens >= PROB_THRESHOLD) ? rv : xv[k];
    }
}

extern "C" void kernel_launch(void* const* d_in, const int* in_sizes, int n_in,
                              void* d_out, int out_size, void* d_ws, size_t ws_size,
                              hipStream_t stream) {
    const float* x    = (const float*)d_in[0];
    const float* kde  = (const float*)d_in[1];
    const float* repl = (const float*)d_in[2];
    float* out        = (float*)d_out;

    const int rows  = in_sizes[0] / F;   // B*S = 2048
    const int total = in_sizes[0];       // 1,048,576

    const size_t need = (size_t)(4 * F + F * G) * sizeof(float);
    if (ws_size >= need) {
        float* scale = (float*)d_ws;
        float* coef  = scale + F;
        float* t0    = coef + F;
        float* invht = t0 + F;
        float* table = invht + F;        // [F][G]
        kde_stats<<<F / 8, 512, 0, stream>>>(kde, scale, coef, t0, invht);
        kde_build<<<F, G, 0, stream>>>(kde, scale, coef, t0, invht, table);
        kde_apply<<<total / 256, 256, 0, stream>>>(x, kde, repl, scale, coef, t0,
                                                   invht, table, out);
    } else {
        kde_mask_fused<<<rows / ROWS, 512, 0, stream>>>(x, kde, repl, out);
    }
}

// Round 6
// 23.847 us; speedup vs baseline: 1.2278x; 1.2278x over previous
//
#include <hip/hip_runtime.h>
#include <math.h>

// Problem constants (from reference setup_inputs): B=2, S=1024, F=512, N=128.
#define F 512
#define N 128
#define G 256                 // density-table points per feature
#define ROWS 4                // fallback kernel rows/block

constexpr float PROB_THRESHOLD = 0.3f;
constexpr float MARGIN         = 1e-4f;   // certified interp error bound ~2e-5, 5x headroom
constexpr float INV_SQRT_2PI   = 0.3989422804014327f;
// exp(-0.5*z^2) = exp2(-(z*SCALE_C)^2), SCALE_C = sqrt(0.5*log2(e))
constexpr float SCALE_C = 0.8493218002880191f;
// 128^(-0.2)  (Scott's rule factor)
constexpr float FACTOR  = 0.37892914162759955f;
constexpr float PAD_T   = 8.0f;           // grid padding in t-units (exp2(-64)~0)

// ---------------------------------------------------------------------------
// Kernel A: one block per feature (512 blocks x 256 threads).
// Fuses stats (block reduction, one-pass var validated in R4) + density-table
// build (thread g computes grid point g; kde column cached in LDS).
// Also packs per-feature apply constants: const4 = {scale*invht, -t0*invht,
// repl, scale}; coefs[f] for the rare refine path.
// ---------------------------------------------------------------------------
__global__ __launch_bounds__(G) void kde_prep(const float* __restrict__ kde,
                                              const float* __restrict__ repl,
                                              float* __restrict__ table,
                                              float4* __restrict__ const4,
                                              float* __restrict__ coefs) {
    const int f    = blockIdx.x;
    const int tid  = threadIdx.x;
    const int lane = tid & 63;
    const int wv   = tid >> 6;

    __shared__ float vbuf[N];
    __shared__ float redS[4], redSS[4], redMN[4], redMX[4];

    float v = 0.f, vmn = INFINITY, vmx = -INFINITY;
    if (tid < N) {
        v = kde[tid * F + f];
        vbuf[tid] = v;
        vmn = v;
        vmx = v;
    }
    float s  = v;
    float ss = v * v;
#pragma unroll
    for (int off = 32; off >= 1; off >>= 1) {
        s   += __shfl_xor(s, off);
        ss  += __shfl_xor(ss, off);
        vmn  = fminf(vmn, __shfl_xor(vmn, off));
        vmx  = fmaxf(vmx, __shfl_xor(vmx, off));
    }
    if (lane == 0) { redS[wv] = s; redSS[wv] = ss; redMN[wv] = vmn; redMX[wv] = vmx; }
    __syncthreads();

    // Every thread recomputes the (identical) scalars from the 4 partials.
    const float S  = (redS[0] + redS[1]) + (redS[2] + redS[3]);
    const float SS = (redSS[0] + redSS[1]) + (redSS[2] + redSS[3]);
    const float MN = fminf(fminf(redMN[0], redMN[1]), fminf(redMN[2], redMN[3]));
    const float MX = fmaxf(fmaxf(redMX[0], redMX[1]), fmaxf(redMX[2], redMX[3]));

    const float mean  = S * (1.0f / N);
    const float var   = (SS - S * mean) * (1.0f / (N - 1));
    const float bw    = FACTOR * sqrtf(var);
    const float scale = SCALE_C / bw;
    const float coef  = INV_SQRT_2PI / bw;
    const float t0    = MN * scale - PAD_T;
    const float t1    = MX * scale + PAD_T;
    const float invht = (float)(G - 1) / (t1 - t0);
    const float ht    = 1.0f / invht;

    // Build: thread tid owns grid point tid (128 exps, LDS-broadcast reads).
    const float tg = fmaf((float)tid, ht, t0);
    float acc = 0.f;
#pragma unroll 8
    for (int n = 0; n < N; ++n) {
        const float a = vbuf[n] * scale;
        const float z = tg - a;
        acc += __builtin_amdgcn_exp2f(-(z * z));
    }
    table[f * G + tid] = (acc * (1.0f / N)) * coef;

    if (tid == 0) {
        const4[f] = make_float4(scale * invht, -t0 * invht, repl[f], scale);
        coefs[f]  = coef;
    }
}

// ---------------------------------------------------------------------------
// Kernel B: apply. One thread per element; single float4 constant load;
// cubic Lagrange interp (identical arithmetic to validated R5); ambiguous
// band recomputed exactly with R3 arithmetic — now UNROLLED so the 128 kde
// loads pipeline instead of serializing on latency.
// ---------------------------------------------------------------------------
__global__ __launch_bounds__(256) void kde_apply(const float* __restrict__ x,
                                                 const float* __restrict__ kde,
                                                 const float* __restrict__ table,
                                                 const float4* __restrict__ const4,
                                                 const float* __restrict__ coefs,
                                                 float* __restrict__ out) {
    const int e = blockIdx.x * 256 + threadIdx.x;
    const int f = e & (F - 1);

    const float  xv = x[e];
    const float4 c  = const4[f];            // {scale*invht, -t0*invht, rv, scale}
    const float  u  = fmaf(xv, c.x, c.y);

    float res = xv;
    if (u >= 1.0f && u < (float)(G - 2)) {
        const int   i    = (int)u;
        const float sfr  = u - (float)i;
        const int   base = f * G + i - 1;
        const float p0 = table[base + 0];
        const float p1 = table[base + 1];
        const float p2 = table[base + 2];
        const float p3 = table[base + 3];
        const float sm1 = sfr - 1.0f, sm2 = sfr - 2.0f, sp1 = sfr + 1.0f;
        const float w0 = -sfr * sm1 * sm2 * (1.0f / 6.0f);
        const float w1 = sp1 * sm1 * sm2 * 0.5f;
        const float w2 = -sp1 * sfr * sm2 * 0.5f;
        const float w3 = sp1 * sfr * sm1 * (1.0f / 6.0f);
        const float dens = w0 * p0 + w1 * p1 + w2 * p2 + w3 * p3;

        if (dens >= PROB_THRESHOLD + MARGIN) {
            res = c.z;
        } else if (dens >= PROB_THRESHOLD - MARGIN) {
            // Exact recompute — bitwise R3 arithmetic (validated absmax=0).
            const float scale = c.w;
            const float coef  = coefs[f];
            const float t     = xv * scale;
            const float t2    = t + t;
            const float et    = __builtin_amdgcn_exp2f(-(t * t));
            float acc = 0.f;
#pragma unroll 8
            for (int n = 0; n < N; ++n) {
                const float a   = kde[n * F + f] * scale;
                const float na2 = -(a * a);
                acc += __builtin_amdgcn_exp2f(fmaf(t2, a, na2));
            }
            const float sum   = acc * et;
            const float dens2 = (sum * (1.0f / N)) * coef;
            res = (dens2 >= PROB_THRESHOLD) ? c.z : xv;
        }
    }
    // (u out of range => nearest sample >= ~7.9 t-units => dens < 1e-18 => keep x)

    out[e] = res;
}

// ---------------------------------------------------------------------------
// Fallback (ws too small): R4's validated fused direct kernel, unchanged.
// ---------------------------------------------------------------------------
__global__ __launch_bounds__(512) void kde_mask_fused(const float* __restrict__ x,
                                                      const float* __restrict__ kde,
                                                      const float* __restrict__ repl,
                                                      float* __restrict__ out) {
    const int f  = threadIdx.x;
    const int r0 = blockIdx.x * ROWS;

    float s = 0.f, ss = 0.f;
#pragma unroll 8
    for (int n = 0; n < N; ++n) {
        const float v = kde[n * F + f];
        s += v;
        ss = fmaf(v, v, ss);
    }
    const float mean  = s * (1.0f / N);
    const float var   = (ss - s * mean) * (1.0f / (N - 1));
    const float bw    = FACTOR * sqrtf(var);
    const float scale = SCALE_C / bw;
    const float coef  = INV_SQRT_2PI / bw;

    float xv[ROWS], t2[ROWS], et[ROWS], acc[ROWS];
#pragma unroll
    for (int k = 0; k < ROWS; ++k) {
        xv[k]  = x[(r0 + k) * F + f];
        const float t = xv[k] * scale;
        t2[k]  = t + t;
        et[k]  = __builtin_amdgcn_exp2f(-(t * t));
        acc[k] = 0.f;
    }
#pragma unroll 8
    for (int n = 0; n < N; ++n) {
        const float v   = kde[n * F + f];
        const float a   = v * scale;
        const float na2 = -(a * a);
#pragma unroll
        for (int k = 0; k < ROWS; ++k) {
            acc[k] += __builtin_amdgcn_exp2f(fmaf(t2[k], a, na2));
        }
    }
    const float rv = repl[f];
#pragma unroll
    for (int k = 0; k < ROWS; ++k) {
        const float sum  = acc[k] * et[k];
        const float dens = (sum * (1.0f / N)) * coef;
        out[(r0 + k) * F + f] = (dens >= PROB_THRESHOLD) ? rv : xv[k];
    }
}

extern "C" void kernel_launch(void* const* d_in, const int* in_sizes, int n_in,
                              void* d_out, int out_size, void* d_ws, size_t ws_size,
                              hipStream_t stream) {
    const float* x    = (const float*)d_in[0];
    const float* kde  = (const float*)d_in[1];
    const float* repl = (const float*)d_in[2];
    float* out        = (float*)d_out;

    const int rows  = in_sizes[0] / F;   // B*S = 2048
    const int total = in_sizes[0];       // 1,048,576

    const size_t need = (size_t)(F * G) * sizeof(float)   // table
                      + (size_t)F * sizeof(float4)        // const4
                      + (size_t)F * sizeof(float);        // coefs
    if (ws_size >= need) {
        float*  table  = (float*)d_ws;
        float4* const4 = (float4*)(table + (size_t)F * G);  // 512KB offset, 16B-aligned
        float*  coefs  = (float*)(const4 + F);
        kde_prep<<<F, G, 0, stream>>>(kde, repl, table, const4, coefs);
        kde_apply<<<total / 256, 256, 0, stream>>>(x, kde, table, const4, coefs, out);
    } else {
        kde_mask_fused<<<rows / ROWS, 512, 0, stream>>>(x, kde, repl, out);
    }
}